// Round 7
// baseline (437.477 us; speedup 1.0000x reference)
//
#include <hip/hip_runtime.h>
#include <math.h>

typedef __bf16 bf16;
typedef bf16 bf16x8 __attribute__((ext_vector_type(8)));
typedef bf16 bf16x4 __attribute__((ext_vector_type(4)));
typedef float f32x4 __attribute__((ext_vector_type(4)));

#define NROWS 16384
#define HID 2048

// ---------------- async global->LDS helper ----------------
__device__ __forceinline__ void gload_lds16(const bf16* g, bf16* l) {
  __builtin_amdgcn_global_load_lds((const __attribute__((address_space(1))) void*)g,
                                   (__attribute__((address_space(3))) void*)l,
                                   16, 0, 0);
}

// =====================================================================
// 256x256-tile bf16 GEMM, BK=32, 4-buffer LDS pipeline (3 tiles ahead),
// counted-vmcnt ladder 8/4/0, m201-style 4-phase-per-tile schedule:
// each phase = {1 stage op, phase ds_reads, BAR, lgkm0, setprio1,
// 8 MFMA (one quadrant), setprio0, BAR}.
// C = act(A * B^T + bias).  A [M,K], B [N,K] row-major bf16, C [M,N] bf16.
// Grid: 512 blocks (64 bm x 8 bn, XCD-swizzled), 512 threads (8 waves 2Mx4N).
// LDS: 4 bufs x (A 256x32 + B 256x32) bf16 = 128 KiB (dynamic).
// Swizzle (verified 0-conflict): within each 64B row-segment, phys slot kp
// holds logical k = kp ^ ((row>>1)&3); applied on the global source side
// (LDS dest stays linear per global_load_lds rules) and on the ds_read side.
// Race audit: stage in tile t writes buf (t+3)&3 == (t-1)&3, whose last
// reads completed before tile t-1's P2 MFMA (lgkm0) and are separated from
// this stage by >=2 barriers. Boundary vmcnt(8) drains exactly tile t+1's
// 4 loads; the closing BAR makes them visible to all waves.
// =====================================================================
#define MF(a, b, c) __builtin_amdgcn_mfma_f32_16x16x32_bf16((a), (b), (c), 0, 0, 0)

#define BAR()                                  \
  asm volatile("" ::: "memory");               \
  __builtin_amdgcn_s_barrier();                \
  asm volatile("" ::: "memory");

#define LGKM0()                                           \
  asm volatile("s_waitcnt lgkmcnt(0)" ::: "memory");      \
  __builtin_amdgcn_sched_barrier(0);

template <int K, bool RELU>
__global__ __launch_bounds__(512, 2) void gemm256(const bf16* __restrict__ A,
                                                  const bf16* __restrict__ B,
                                                  const float* __restrict__ bias,
                                                  bf16* __restrict__ C, int N) {
  extern __shared__ bf16 smem[];
  constexpr int NT = K / 32;
  const int tid = threadIdx.x;
  const int lane = tid & 63;
  const int w = tid >> 6;          // wave 0..7
  const int wr = w >> 2, wc = w & 3;

  // XCD-aware swizzle: XCD c gets bm in [c*8,c*8+8) x all 8 bn.
  const int xc = blockIdx.x & 7, xl = blockIdx.x >> 3;
  const int bm = xc * 8 + (xl >> 3);
  const int bn = xl & 7;

  const bf16* Abase = A + (size_t)bm * 256 * K;
  const bf16* Bbase = B + (size_t)bn * 256 * K;

  // staging source offsets (global side of the swizzle)
  const int r0 = tid >> 2;          // 0..127
  const int r1 = r0 + 128;          // 128..255
  const int kp = tid & 3;
  const size_t offS0 = (size_t)r0 * K + ((kp ^ ((r0 >> 1) & 3)) * 8);
  const size_t offS1 = (size_t)r1 * K + ((kp ^ ((r1 >> 1) & 3)) * 8);

  // read offsets (same involution), elems within one buffer
  int offRA[8], offRB[4];
  const int kk = lane >> 4;         // logical k-slot 0..3
#pragma unroll
  for (int mi = 0; mi < 8; ++mi) {
    const int r = wr * 128 + mi * 16 + (lane & 15);
    offRA[mi] = (r * 4 + (kk ^ ((r >> 1) & 3))) * 8;
  }
#pragma unroll
  for (int ni = 0; ni < 4; ++ni) {
    const int r = wc * 64 + ni * 16 + (lane & 15);
    offRB[ni] = (r * 4 + (kk ^ ((r >> 1) & 3))) * 8 + 8192;
  }

  f32x4 acc[8][4] = {};
  bf16x8 aU[4], aL[4], bL[2], bR[2];

#define LD8(off) (*(const bf16x8*)(smem + (off)))

  // one stage op (1 gload_lds per wave); op 0..3 = {A-lo, A-hi, B-lo, B-hi}
#define STAGE1(t, b, op)                                                     \
  {                                                                          \
    bf16* d = smem + (b) * 16384 + (op) * 4096 + w * 512;                    \
    const bf16* g = ((op) < 2 ? Abase : Bbase) + (size_t)(t) * 32 +          \
                    (((op) & 1) ? offS1 : offS0);                            \
    gload_lds16(g, d);                                                       \
  }

#define STAGE(t, b)                                                          \
  STAGE1(t, b, 0) STAGE1(t, b, 1) STAGE1(t, b, 2) STAGE1(t, b, 3)

#define MF8(AV, BV, mh, nh)                                                  \
  __builtin_amdgcn_s_setprio(1);                                             \
  acc[(mh)*4+0][(nh)*2+0] = MF(AV[0], BV[0], acc[(mh)*4+0][(nh)*2+0]);       \
  acc[(mh)*4+0][(nh)*2+1] = MF(AV[0], BV[1], acc[(mh)*4+0][(nh)*2+1]);       \
  acc[(mh)*4+1][(nh)*2+0] = MF(AV[1], BV[0], acc[(mh)*4+1][(nh)*2+0]);       \
  acc[(mh)*4+1][(nh)*2+1] = MF(AV[1], BV[1], acc[(mh)*4+1][(nh)*2+1]);       \
  acc[(mh)*4+2][(nh)*2+0] = MF(AV[2], BV[0], acc[(mh)*4+2][(nh)*2+0]);       \
  acc[(mh)*4+2][(nh)*2+1] = MF(AV[2], BV[1], acc[(mh)*4+2][(nh)*2+1]);       \
  acc[(mh)*4+3][(nh)*2+0] = MF(AV[3], BV[0], acc[(mh)*4+3][(nh)*2+0]);       \
  acc[(mh)*4+3][(nh)*2+1] = MF(AV[3], BV[1], acc[(mh)*4+3][(nh)*2+1]);       \
  __builtin_amdgcn_s_setprio(0);

  // prologue: tiles 0,1,2 in flight; drain tile 0 (oldest 4 of 12)
  STAGE(0, 0); STAGE(1, 1); STAGE(2, 2);
  asm volatile("s_waitcnt vmcnt(8)" ::: "memory");
  BAR();

  for (int t = 0; t < NT; ++t) {
    const int bb = (t & 3) * 16384;
    const int sb = (t + 3) & 3;
    const bool st = (t + 3) < NT;

    // ---- P0: quadrant (aU, bL) ----
    if (st) STAGE1(t + 3, sb, 0);
#pragma unroll
    for (int i = 0; i < 4; ++i) aU[i] = LD8(bb + offRA[i]);
#pragma unroll
    for (int i = 0; i < 2; ++i) bL[i] = LD8(bb + offRB[i]);
    BAR();
    LGKM0();
    MF8(aU, bL, 0, 0);
    BAR();

    // ---- P1: quadrant (aL, bL) ----
    if (st) STAGE1(t + 3, sb, 1);
#pragma unroll
    for (int i = 0; i < 4; ++i) aL[i] = LD8(bb + offRA[4 + i]);
    BAR();
    LGKM0();
    MF8(aL, bL, 1, 0);
    BAR();

    // ---- P2: quadrant (aU, bR) ----
    if (st) STAGE1(t + 3, sb, 2);
#pragma unroll
    for (int i = 0; i < 2; ++i) bR[i] = LD8(bb + offRB[2 + i]);
    BAR();
    LGKM0();
    MF8(aU, bR, 0, 1);
    BAR();

    // ---- P3: quadrant (aL, bR) + tile-boundary ladder ----
    if (st) STAGE1(t + 3, sb, 3);
    BAR();
    MF8(aL, bR, 1, 1);
    if (t + 1 < NT) {
      if (t + 3 < NT)      asm volatile("s_waitcnt vmcnt(8)" ::: "memory");
      else if (t + 2 < NT) asm volatile("s_waitcnt vmcnt(4)" ::: "memory");
      else                 asm volatile("s_waitcnt vmcnt(0)" ::: "memory");
    }
    BAR();
  }

  // epilogue: bias + optional relu, bf16 store
  const int crow0 = bm * 256 + wr * 128 + (lane >> 4) * 4;
  const int ccol0 = bn * 256 + wc * 64 + (lane & 15);
#pragma unroll
  for (int mi = 0; mi < 8; ++mi) {
#pragma unroll
    for (int ni = 0; ni < 4; ++ni) {
      const int col = ccol0 + ni * 16;
      const float bvv = bias[col];
#pragma unroll
      for (int j = 0; j < 4; ++j) {
        const int row = crow0 + mi * 16 + j;
        float v = acc[mi][ni][j] + bvv;
        if (RELU) v = fmaxf(v, 0.f);
        C[(size_t)row * N + col] = (bf16)v;
      }
    }
  }
}

// ---------------- fused f32->bf16 convert + param sum-of-squares ----------------
// MLP-4: each bulk iteration issues 4 independent coalesced float4 loads.
struct CvtSqArgs {
  const float* src[6];  // X, W1, W2, W3, b1, b2
  bf16* dst[6];         // Xb, W1b, W2b, W3b, null, null
  int n4[6];
  int dosq[6];
};

__global__ __launch_bounds__(256) void cvtsq_kernel(CvtSqArgs a, float* __restrict__ acc) {
  float s = 0.f;
  const int S = gridDim.x * blockDim.x;          // 131072 (power of 2)
  const int gid = blockIdx.x * blockDim.x + threadIdx.x;
#pragma unroll 1
  for (int seg = 0; seg < 6; ++seg) {
    const float4* __restrict__ src = (const float4*)a.src[seg];
    bf16x4* __restrict__ dst = (bf16x4*)a.dst[seg];
    const int n4 = a.n4[seg];
    const bool dq = a.dosq[seg] != 0;
    const int nb = n4 & ~(4 * S - 1);            // bulk region (multiple of 4S)
    for (int i = gid; i < nb; i += 4 * S) {
      float4 v0 = src[i];
      float4 v1 = src[i + S];
      float4 v2 = src[i + 2 * S];
      float4 v3 = src[i + 3 * S];
      if (dst) {
        bf16x4 o0, o1, o2, o3;
        o0[0]=(bf16)v0.x; o0[1]=(bf16)v0.y; o0[2]=(bf16)v0.z; o0[3]=(bf16)v0.w;
        o1[0]=(bf16)v1.x; o1[1]=(bf16)v1.y; o1[2]=(bf16)v1.z; o1[3]=(bf16)v1.w;
        o2[0]=(bf16)v2.x; o2[1]=(bf16)v2.y; o2[2]=(bf16)v2.z; o2[3]=(bf16)v2.w;
        o3[0]=(bf16)v3.x; o3[1]=(bf16)v3.y; o3[2]=(bf16)v3.z; o3[3]=(bf16)v3.w;
        dst[i] = o0; dst[i + S] = o1; dst[i + 2 * S] = o2; dst[i + 3 * S] = o3;
      }
      if (dq) {
        s += v0.x*v0.x + v0.y*v0.y + v0.z*v0.z + v0.w*v0.w;
        s += v1.x*v1.x + v1.y*v1.y + v1.z*v1.z + v1.w*v1.w;
        s += v2.x*v2.x + v2.y*v2.y + v2.z*v2.z + v2.w*v2.w;
        s += v3.x*v3.x + v3.y*v3.y + v3.z*v3.z + v3.w*v3.w;
      }
    }
    for (int i = nb + gid; i < n4; i += S) {
      float4 v = src[i];
      if (dst) {
        bf16x4 o;
        o[0]=(bf16)v.x; o[1]=(bf16)v.y; o[2]=(bf16)v.z; o[3]=(bf16)v.w;
        dst[i] = o;
      }
      if (dq) s += v.x*v.x + v.y*v.y + v.z*v.z + v.w*v.w;
    }
  }
#pragma unroll
  for (int off = 32; off; off >>= 1) s += __shfl_xor(s, off, 64);
  if ((threadIdx.x & 63) == 0) atomicAdd(&acc[1], s);
}

// ---------------- fused GEMM3 (N=10) + log-softmax + gather + sum ----------------
__global__ __launch_bounds__(256) void loss_kernel(const bf16* __restrict__ h2,
                                                   const bf16* __restrict__ W3b,
                                                   const float* __restrict__ b3,
                                                   const int* __restrict__ Y,
                                                   float* __restrict__ acc) {
  __shared__ bf16 w3s[10 * HID];
  for (int i = threadIdx.x; i < 10 * HID / 8; i += 256)
    ((bf16x8*)w3s)[i] = ((const bf16x8*)W3b)[i];
  __syncthreads();

  const int lane = threadIdx.x & 63;
  const int w = threadIdx.x >> 6;
  const int nwave = gridDim.x * 4;
  float lsum = 0.f;

  for (int row = blockIdx.x * 4 + w; row < NROWS; row += nwave) {
    float p[10];
#pragma unroll
    for (int c = 0; c < 10; ++c) p[c] = 0.f;
    const bf16* hrow = h2 + (size_t)row * HID;
#pragma unroll
    for (int it = 0; it < 4; ++it) {
      const int k = it * 512 + lane * 8;
      bf16x8 hv = *(const bf16x8*)&hrow[k];
      float hf[8];
#pragma unroll
      for (int j = 0; j < 8; ++j) hf[j] = (float)hv[j];
#pragma unroll
      for (int c = 0; c < 10; ++c) {
        bf16x8 wv = *(const bf16x8*)&w3s[c * HID + k];
        float dp = 0.f;
#pragma unroll
        for (int j = 0; j < 8; ++j) dp += hf[j] * (float)wv[j];
        p[c] += dp;
      }
    }
#pragma unroll
    for (int off = 32; off; off >>= 1)
#pragma unroll
      for (int c = 0; c < 10; ++c) p[c] += __shfl_xor(p[c], off, 64);

    float lg[10], m = -1e30f;
#pragma unroll
    for (int c = 0; c < 10; ++c) { lg[c] = p[c] + b3[c]; m = fmaxf(m, lg[c]); }
    float s = 0.f;
#pragma unroll
    for (int c = 0; c < 10; ++c) s += expf(lg[c] - m);
    const float lse = m + logf(s);
    const int y = Y[row];
    float ly = 0.f;
#pragma unroll
    for (int c = 0; c < 10; ++c) ly += (c == y) ? lg[c] : 0.f;
    lsum += ly - lse;
  }
  if (lane == 0) atomicAdd(&acc[0], lsum);
}

__global__ void finalize_kernel(float* __restrict__ out, const float* __restrict__ acc,
                                const float* __restrict__ b3, double dterm) {
  double sq = (double)acc[1];
  for (int i = 0; i < 10; ++i) sq += (double)b3[i] * (double)b3[i];
  out[0] = (float)((double)acc[0] - 0.5 * (sq / 100.0 + dterm));
}

// ---------------- launch ----------------
extern "C" void kernel_launch(void* const* d_in, const int* in_sizes, int n_in,
                              void* d_out, int out_size, void* d_ws, size_t ws_size,
                              hipStream_t stream) {
  const float* X  = (const float*)d_in[0];
  const int*   Y  = (const int*)d_in[1];
  const float* W1 = (const float*)d_in[2];
  const float* b1 = (const float*)d_in[3];
  const float* W2 = (const float*)d_in[4];
  const float* b2 = (const float*)d_in[5];
  const float* W3 = (const float*)d_in[6];
  const float* b3 = (const float*)d_in[7];
  float* out = (float*)d_out;

  char* ws = (char*)d_ws;
  size_t off = 0;
  auto alloc = [&](size_t bytes) -> void* {
    void* p = ws + off;
    off += (bytes + 255) & ~(size_t)255;
    return p;
  };
  bf16* Xb  = (bf16*)alloc((size_t)NROWS * 1024 * 2);
  bf16* W1b = (bf16*)alloc((size_t)HID * 1024 * 2);
  bf16* W2b = (bf16*)alloc((size_t)HID * HID * 2);
  bf16* W3b = (bf16*)alloc((size_t)10 * HID * 2);
  bf16* h1  = (bf16*)alloc((size_t)NROWS * HID * 2);
  bf16* h2  = (bf16*)alloc((size_t)NROWS * HID * 2);
  float* acc = (float*)alloc(256);

  hipMemsetAsync(acc, 0, 16, stream);

  // fused convert + sum-of-squares (b3 handled in finalize)
  CvtSqArgs ca;
  ca.src[0] = X;  ca.dst[0] = Xb;  ca.n4[0] = NROWS * 1024 / 4; ca.dosq[0] = 0;
  ca.src[1] = W1; ca.dst[1] = W1b; ca.n4[1] = HID * 1024 / 4;   ca.dosq[1] = 1;
  ca.src[2] = W2; ca.dst[2] = W2b; ca.n4[2] = HID * HID / 4;    ca.dosq[2] = 1;
  ca.src[3] = W3; ca.dst[3] = W3b; ca.n4[3] = 10 * HID / 4;     ca.dosq[3] = 1;
  ca.src[4] = b1; ca.dst[4] = nullptr; ca.n4[4] = HID / 4;      ca.dosq[4] = 1;
  ca.src[5] = b2; ca.dst[5] = nullptr; ca.n4[5] = HID / 4;      ca.dosq[5] = 1;
  cvtsq_kernel<<<512, 256, 0, stream>>>(ca, acc);

  // allow 128 KiB dynamic LDS (host-side attr, capture-safe)
  hipFuncSetAttribute((const void*)gemm256<1024, true>,
                      hipFuncAttributeMaxDynamicSharedMemorySize, 131072);
  hipFuncSetAttribute((const void*)gemm256<2048, true>,
                      hipFuncAttributeMaxDynamicSharedMemorySize, 131072);

  // GEMM1: h1 = relu(X[16384,1024] * W1[2048,1024]^T + b1)
  gemm256<1024, true><<<512, 512, 131072, stream>>>(Xb, W1b, b1, h1, HID);
  // GEMM2: h2 = relu(h1 * W2[2048,2048]^T + b2)
  gemm256<2048, true><<<512, 512, 131072, stream>>>(h1, W2b, b2, h2, HID);

  loss_kernel<<<1024, 256, 0, stream>>>(h2, W3b, b3, Y, acc);

  long long d = 0;
  for (int i = 2; i < 8; ++i) d += in_sizes[i];
  double dterm = (double)d * log(2.0 * M_PI * 100.0);
  finalize_kernel<<<1, 1, 0, stream>>>(out, acc, b3, dterm);
}

// Round 8
// 409.948 us; speedup vs baseline: 1.0672x; 1.0672x over previous
//
#include <hip/hip_runtime.h>
#include <math.h>

typedef __bf16 bf16;
typedef bf16 bf16x8 __attribute__((ext_vector_type(8)));
typedef bf16 bf16x4 __attribute__((ext_vector_type(4)));
typedef float f32x4 __attribute__((ext_vector_type(4)));

#define NROWS 16384
#define HID 2048

// ---------------- async global->LDS helper ----------------
__device__ __forceinline__ void gload_lds16(const bf16* g, bf16* l) {
  __builtin_amdgcn_global_load_lds((const __attribute__((address_space(1))) void*)g,
                                   (__attribute__((address_space(3))) void*)l,
                                   16, 0, 0);
}

#define MF(a, b, c) __builtin_amdgcn_mfma_f32_16x16x32_bf16((a), (b), (c), 0, 0, 0)

#define BAR()                                  \
  asm volatile("" ::: "memory");               \
  __builtin_amdgcn_s_barrier();                \
  asm volatile("" ::: "memory");

#define LGKM0()                                           \
  asm volatile("s_waitcnt lgkmcnt(0)" ::: "memory");      \
  __builtin_amdgcn_sched_barrier(0);

// =====================================================================
// Kernel A (round-6 proven, used for GEMM1): 256x256 tile, BK=32,
// 4-buffer LDS pipeline, vmcnt 8/4/0 ladder, read-hoisted ds_reads.
// =====================================================================
template <int K, bool RELU>
__global__ __launch_bounds__(512, 2) void gemm_r6(const bf16* __restrict__ A,
                                                  const bf16* __restrict__ B,
                                                  const float* __restrict__ bias,
                                                  bf16* __restrict__ C, int N) {
  extern __shared__ bf16 smem[];
  constexpr int NT = K / 32;
  const int tid = threadIdx.x;
  const int lane = tid & 63;
  const int w = tid >> 6;
  const int wr = w >> 2, wc = w & 3;

  const int xc = blockIdx.x & 7, xl = blockIdx.x >> 3;
  const int bm = xc * 8 + (xl >> 3);
  const int bn = xl & 7;

  const bf16* Abase = A + (size_t)bm * 256 * K;
  const bf16* Bbase = B + (size_t)bn * 256 * K;

  const int r0 = tid >> 2;
  const int r1 = r0 + 128;
  const int kp = tid & 3;
  const size_t offS0 = (size_t)r0 * K + ((kp ^ ((r0 >> 1) & 3)) * 8);
  const size_t offS1 = (size_t)r1 * K + ((kp ^ ((r1 >> 1) & 3)) * 8);

  int offRA[8], offRB[4];
  const int kk = lane >> 4;
#pragma unroll
  for (int mi = 0; mi < 8; ++mi) {
    const int r = wr * 128 + mi * 16 + (lane & 15);
    offRA[mi] = (r * 4 + (kk ^ ((r >> 1) & 3))) * 8;
  }
#pragma unroll
  for (int ni = 0; ni < 4; ++ni) {
    const int r = wc * 64 + ni * 16 + (lane & 15);
    offRB[ni] = (r * 4 + (kk ^ ((r >> 1) & 3))) * 8 + 8192;
  }

  f32x4 acc[8][4] = {};
  bf16x8 a0[4], a1[4], b0[4], b1[4];

#define LD8(off) (*(const bf16x8*)(smem + (off)))

#define R6STAGE(t, b)                                                 \
  {                                                                   \
    const bf16* As = Abase + (size_t)(t) * 32;                        \
    const bf16* Bs = Bbase + (size_t)(t) * 32;                        \
    bf16* d = smem + (b) * 16384 + w * 512;                           \
    gload_lds16(As + offS0, d);                                       \
    gload_lds16(As + offS1, d + 4096);                                \
    gload_lds16(Bs + offS0, d + 8192);                                \
    gload_lds16(Bs + offS1, d + 12288);                               \
  }

#define R6MFMA16(AV, BV, mh)                                         \
  __builtin_amdgcn_s_setprio(1);                                     \
  acc[(mh)*4+0][0] = MF(AV[0], BV[0], acc[(mh)*4+0][0]);             \
  acc[(mh)*4+0][1] = MF(AV[0], BV[1], acc[(mh)*4+0][1]);             \
  acc[(mh)*4+0][2] = MF(AV[0], BV[2], acc[(mh)*4+0][2]);             \
  acc[(mh)*4+0][3] = MF(AV[0], BV[3], acc[(mh)*4+0][3]);             \
  acc[(mh)*4+1][0] = MF(AV[1], BV[0], acc[(mh)*4+1][0]);             \
  acc[(mh)*4+1][1] = MF(AV[1], BV[1], acc[(mh)*4+1][1]);             \
  acc[(mh)*4+1][2] = MF(AV[1], BV[2], acc[(mh)*4+1][2]);             \
  acc[(mh)*4+1][3] = MF(AV[1], BV[3], acc[(mh)*4+1][3]);             \
  acc[(mh)*4+2][0] = MF(AV[2], BV[0], acc[(mh)*4+2][0]);             \
  acc[(mh)*4+2][1] = MF(AV[2], BV[1], acc[(mh)*4+2][1]);             \
  acc[(mh)*4+2][2] = MF(AV[2], BV[2], acc[(mh)*4+2][2]);             \
  acc[(mh)*4+2][3] = MF(AV[2], BV[3], acc[(mh)*4+2][3]);             \
  acc[(mh)*4+3][0] = MF(AV[3], BV[0], acc[(mh)*4+3][0]);             \
  acc[(mh)*4+3][1] = MF(AV[3], BV[1], acc[(mh)*4+3][1]);             \
  acc[(mh)*4+3][2] = MF(AV[3], BV[2], acc[(mh)*4+3][2]);             \
  acc[(mh)*4+3][3] = MF(AV[3], BV[3], acc[(mh)*4+3][3]);             \
  __builtin_amdgcn_s_setprio(0);

  R6STAGE(0, 0); R6STAGE(1, 1); R6STAGE(2, 2);
  asm volatile("s_waitcnt vmcnt(8)" ::: "memory");
  BAR();
  {
#pragma unroll
    for (int i = 0; i < 4; ++i) b0[i] = LD8(offRB[i]);
#pragma unroll
    for (int i = 0; i < 4; ++i) a0[i] = LD8(offRA[i]);
  }

  for (int t = 0; t < NT; t += 2) {
    if (t + 3 < NT) R6STAGE(t + 3, (t + 3) & 3);
    {
      const int bb = (t & 3) * 16384;
#pragma unroll
      for (int i = 0; i < 4; ++i) a1[i] = LD8(bb + offRA[4 + i]);
    }
    R6MFMA16(a0, b0, 0);
    LGKM0();
    if (t + 3 < NT)      asm volatile("s_waitcnt vmcnt(8)" ::: "memory");
    else if (t + 2 < NT) asm volatile("s_waitcnt vmcnt(4)" ::: "memory");
    else                 asm volatile("s_waitcnt vmcnt(0)" ::: "memory");
    BAR();
    {
      const int nb = ((t + 1) & 3) * 16384;
#pragma unroll
      for (int i = 0; i < 4; ++i) b1[i] = LD8(nb + offRB[i]);
#pragma unroll
      for (int i = 0; i < 4; ++i) a0[i] = LD8(nb + offRA[i]);
    }
    R6MFMA16(a1, b0, 1);

    if (t + 4 < NT) R6STAGE(t + 4, (t + 4) & 3);
    {
      const int bb = ((t + 1) & 3) * 16384;
#pragma unroll
      for (int i = 0; i < 4; ++i) a1[i] = LD8(bb + offRA[4 + i]);
    }
    R6MFMA16(a0, b1, 0);
    LGKM0();
    if (t + 4 < NT)      asm volatile("s_waitcnt vmcnt(8)" ::: "memory");
    else if (t + 3 < NT) asm volatile("s_waitcnt vmcnt(4)" ::: "memory");
    else                 asm volatile("s_waitcnt vmcnt(0)" ::: "memory");
    if (t + 2 < NT) {
      BAR();
      const int nb = ((t + 2) & 3) * 16384;
#pragma unroll
      for (int i = 0; i < 4; ++i) b0[i] = LD8(nb + offRB[i]);
#pragma unroll
      for (int i = 0; i < 4; ++i) a0[i] = LD8(nb + offRA[i]);
    }
    R6MFMA16(a1, b1, 1);
  }

  const int crow0 = bm * 256 + wr * 128 + (lane >> 4) * 4;
  const int ccol0 = bn * 256 + wc * 64 + (lane & 15);
#pragma unroll
  for (int mi = 0; mi < 8; ++mi) {
#pragma unroll
    for (int ni = 0; ni < 4; ++ni) {
      const int col = ccol0 + ni * 16;
      const float bvv = bias[col];
#pragma unroll
      for (int j = 0; j < 4; ++j) {
        const int row = crow0 + mi * 16 + j;
        float v = acc[mi][ni][j] + bvv;
        if (RELU) v = fmaxf(v, 0.f);
        C[(size_t)row * N + col] = (bf16)v;
      }
    }
  }
}
#undef R6STAGE
#undef R6MFMA16

// =====================================================================
// Kernel B (m201-faithful, used for GEMM2): 256x256 tile, BK=64,
// 2-buffer LDS, 4 quadrant-phases per K-tile (16 MFMA each), staggered
// half-tile staging, boundary vmcnt(4) (2 half-tiles ride across).
// Quadrant order Q00 -> Q10 -> Q01 -> Q11.
// Stagger: p0 stages (T+1).B-h0 -> buf^1, p1 (T+1).B-h1 -> buf^1,
//          p2 (T+2).A-h0 -> buf,   p3 (T+2).A-h1 -> buf.
// Race audit: A-halves of tile T dead after T.p1, B-halves after T.p2;
// every overwrite lands >=1 barrier-pair after the last read. Boundary
// vmcnt(4) at T.p3 drains exactly through (T+1).B-h1 -> tile T+1 complete.
// Swizzle: 128B rows, phys slot p holds logical slot p ^ (row&7); applied
// on the global source (LDS linear per gload_lds) and the ds_read side.
// =====================================================================
template <int K, bool RELU>
__global__ __launch_bounds__(512, 2) void gemm_p4(const bf16* __restrict__ A,
                                                  const bf16* __restrict__ B,
                                                  const float* __restrict__ bias,
                                                  bf16* __restrict__ C, int N) {
  extern __shared__ bf16 smem[];
  constexpr int NT = K / 64;
  const int tid = threadIdx.x;
  const int lane = tid & 63;
  const int w = tid >> 6;
  const int wr = w >> 2, wc = w & 3;

  const int xc = blockIdx.x & 7, xl = blockIdx.x >> 3;
  const int bm = xc * 8 + (xl >> 3);
  const int bn = xl & 7;

  const bf16* Abase = A + (size_t)bm * 256 * K;
  const bf16* Bbase = B + (size_t)bn * 256 * K;

  // staging: one op = 512 thr x 16B = 64 rows x 128B; row=tid>>3, phys=tid&7
  const int srow = tid >> 3;
  const int sslot = (tid & 7) ^ (srow & 7);

  // read-side phys slots: logical slot = ksub*4 + (lane>>4); row&7 == lane&7
  const int q0 = (lane >> 4) ^ (lane & 7);
  const int q1 = q0 ^ 4;
  int rA[8], rB[4];
#pragma unroll
  for (int mi = 0; mi < 8; ++mi)
    rA[mi] = (wr * 128 + mi * 16 + (lane & 15)) * 64;
#pragma unroll
  for (int ni = 0; ni < 4; ++ni)
    rB[ni] = 16384 + (wc * 64 + ni * 16 + (lane & 15)) * 64;

  f32x4 acc[8][4] = {};
  // frags: a0 = mi0-3 (x ksub), a1 = mi4-7, b0 = ni0-1, b1 = ni2-3
  bf16x8 a0[8], a1[8], b0[4], b1[4];

  // one stage op: (tile t, isB, half h, op j) -> buf bb
#define SOP(t, isB, h, j, bb)                                                  \
  {                                                                            \
    bf16* d = smem + (bb) * 32768 + (isB) * 16384 + (h) * 8192 + (j) * 4096 +  \
              w * 512;                                                         \
    const bf16* g = ((isB) ? Bbase : Abase) +                                  \
                    (size_t)((h) * 128 + (j) * 64 + srow) * K +                \
                    (size_t)(t) * 64 + sslot * 8;                              \
    gload_lds16(g, d);                                                         \
  }
#define SHALF(t, isB, h, bb) SOP(t, isB, h, 0, bb) SOP(t, isB, h, 1, bb)

  // MFMA quadrant (mh, nh): 4 mi x 2 ni x 2 ksub = 16
#define QMFMA(AV, BV, mh, nh)                                                  \
  __builtin_amdgcn_s_setprio(1);                                               \
  acc[(mh)*4+0][(nh)*2+0] = MF(AV[0], BV[0], acc[(mh)*4+0][(nh)*2+0]);         \
  acc[(mh)*4+0][(nh)*2+1] = MF(AV[0], BV[2], acc[(mh)*4+0][(nh)*2+1]);         \
  acc[(mh)*4+1][(nh)*2+0] = MF(AV[2], BV[0], acc[(mh)*4+1][(nh)*2+0]);         \
  acc[(mh)*4+1][(nh)*2+1] = MF(AV[2], BV[2], acc[(mh)*4+1][(nh)*2+1]);         \
  acc[(mh)*4+2][(nh)*2+0] = MF(AV[4], BV[0], acc[(mh)*4+2][(nh)*2+0]);         \
  acc[(mh)*4+2][(nh)*2+1] = MF(AV[4], BV[2], acc[(mh)*4+2][(nh)*2+1]);         \
  acc[(mh)*4+3][(nh)*2+0] = MF(AV[6], BV[0], acc[(mh)*4+3][(nh)*2+0]);         \
  acc[(mh)*4+3][(nh)*2+1] = MF(AV[6], BV[2], acc[(mh)*4+3][(nh)*2+1]);         \
  acc[(mh)*4+0][(nh)*2+0] = MF(AV[1], BV[1], acc[(mh)*4+0][(nh)*2+0]);         \
  acc[(mh)*4+0][(nh)*2+1] = MF(AV[1], BV[3], acc[(mh)*4+0][(nh)*2+1]);         \
  acc[(mh)*4+1][(nh)*2+0] = MF(AV[3], BV[1], acc[(mh)*4+1][(nh)*2+0]);         \
  acc[(mh)*4+1][(nh)*2+1] = MF(AV[3], BV[3], acc[(mh)*4+1][(nh)*2+1]);         \
  acc[(mh)*4+2][(nh)*2+0] = MF(AV[5], BV[1], acc[(mh)*4+2][(nh)*2+0]);         \
  acc[(mh)*4+2][(nh)*2+1] = MF(AV[5], BV[3], acc[(mh)*4+2][(nh)*2+1]);         \
  acc[(mh)*4+3][(nh)*2+0] = MF(AV[7], BV[1], acc[(mh)*4+3][(nh)*2+0]);         \
  acc[(mh)*4+3][(nh)*2+1] = MF(AV[7], BV[3], acc[(mh)*4+3][(nh)*2+1]);         \
  __builtin_amdgcn_s_setprio(0);

  // prologue: tile0 (all 4 halves) -> buf0, tile1 A-halves -> buf1
  SHALF(0, 0, 0, 0) SHALF(0, 0, 1, 0) SHALF(0, 1, 0, 0) SHALF(0, 1, 1, 0)
  SHALF(1, 0, 0, 1) SHALF(1, 0, 1, 1)
  asm volatile("s_waitcnt vmcnt(4)" ::: "memory");
  BAR();

  for (int T = 0; T < NT; ++T) {
    const int bb = (T & 1) * 32768;
    const int nb = 32768 - bb;
    (void)nb;

    // ---- p0: reads a0+b0 (12), stage (T+1).B h0, MFMA Q00 ----
    if (T + 1 < NT) SHALF(T + 1, 1, 0, (T + 1) & 1)
#pragma unroll
    for (int i = 0; i < 4; ++i) {
      a0[i * 2 + 0] = LD8(bb + rA[i] + q0 * 8);
      a0[i * 2 + 1] = LD8(bb + rA[i] + q1 * 8);
    }
#pragma unroll
    for (int i = 0; i < 2; ++i) {
      b0[i * 2 + 0] = LD8(bb + rB[i] + q0 * 8);
      b0[i * 2 + 1] = LD8(bb + rB[i] + q1 * 8);
    }
    asm volatile("s_waitcnt lgkmcnt(8)" ::: "memory");
    BAR();
    LGKM0();
    QMFMA(a0, b0, 0, 0);
    BAR();

    // ---- p1: reads a1 (8), stage (T+1).B h1, MFMA Q10 ----
    if (T + 1 < NT) SHALF(T + 1, 1, 1, (T + 1) & 1)
#pragma unroll
    for (int i = 0; i < 4; ++i) {
      a1[i * 2 + 0] = LD8(bb + rA[4 + i] + q0 * 8);
      a1[i * 2 + 1] = LD8(bb + rA[4 + i] + q1 * 8);
    }
    BAR();
    LGKM0();
    QMFMA(a1, b0, 1, 0);
    BAR();

    // ---- p2: reads b1 (4), stage (T+2).A h0 -> current buf, MFMA Q01 ----
    if (T + 2 < NT) SHALF(T + 2, 0, 0, T & 1)
#pragma unroll
    for (int i = 0; i < 2; ++i) {
      b1[i * 2 + 0] = LD8(bb + rB[2 + i] + q0 * 8);
      b1[i * 2 + 1] = LD8(bb + rB[2 + i] + q1 * 8);
    }
    BAR();
    LGKM0();
    QMFMA(a0, b1, 0, 1);
    BAR();

    // ---- p3: stage (T+2).A h1, MFMA Q11, boundary vmcnt ----
    if (T + 2 < NT) SHALF(T + 2, 0, 1, T & 1)
    QMFMA(a1, b1, 1, 1);
    if (T + 1 < NT) {
      if (T + 2 < NT) asm volatile("s_waitcnt vmcnt(4)" ::: "memory");
      else            asm volatile("s_waitcnt vmcnt(0)" ::: "memory");
      BAR();
    }
  }
#undef SOP
#undef SHALF
#undef QMFMA

  const int crow0 = bm * 256 + wr * 128 + (lane >> 4) * 4;
  const int ccol0 = bn * 256 + wc * 64 + (lane & 15);
#pragma unroll
  for (int mi = 0; mi < 8; ++mi) {
#pragma unroll
    for (int ni = 0; ni < 4; ++ni) {
      const int col = ccol0 + ni * 16;
      const float bvv = bias[col];
#pragma unroll
      for (int j = 0; j < 4; ++j) {
        const int row = crow0 + mi * 16 + j;
        float v = acc[mi][ni][j] + bvv;
        if (RELU) v = fmaxf(v, 0.f);
        C[(size_t)row * N + col] = (bf16)v;
      }
    }
  }
}

// ---------------- fused f32->bf16 convert + param sum-of-squares ----------------
struct CvtSqArgs {
  const float* src[6];
  bf16* dst[6];
  int n4[6];
  int dosq[6];
};

__global__ __launch_bounds__(256) void cvtsq_kernel(CvtSqArgs a, float* __restrict__ part) {
  float s = 0.f;
  const int S = gridDim.x * blockDim.x;
  const int gid = blockIdx.x * blockDim.x + threadIdx.x;
#pragma unroll 1
  for (int seg = 0; seg < 6; ++seg) {
    const float4* __restrict__ src = (const float4*)a.src[seg];
    bf16x4* __restrict__ dst = (bf16x4*)a.dst[seg];
    const int n4 = a.n4[seg];
    const bool dq = a.dosq[seg] != 0;
    const int nb = n4 & ~(2 * S - 1);
    for (int i = gid; i < nb; i += 2 * S) {
      float4 v0 = src[i];
      float4 v1 = src[i + S];
      if (dst) {
        bf16x4 o0, o1;
        o0[0]=(bf16)v0.x; o0[1]=(bf16)v0.y; o0[2]=(bf16)v0.z; o0[3]=(bf16)v0.w;
        o1[0]=(bf16)v1.x; o1[1]=(bf16)v1.y; o1[2]=(bf16)v1.z; o1[3]=(bf16)v1.w;
        dst[i] = o0; dst[i + S] = o1;
      }
      if (dq) {
        s += v0.x*v0.x + v0.y*v0.y + v0.z*v0.z + v0.w*v0.w;
        s += v1.x*v1.x + v1.y*v1.y + v1.z*v1.z + v1.w*v1.w;
      }
    }
    for (int i = nb + gid; i < n4; i += S) {
      float4 v = src[i];
      if (dst) {
        bf16x4 o;
        o[0]=(bf16)v.x; o[1]=(bf16)v.y; o[2]=(bf16)v.z; o[3]=(bf16)v.w;
        dst[i] = o;
      }
      if (dq) s += v.x*v.x + v.y*v.y + v.z*v.z + v.w*v.w;
    }
  }
#pragma unroll
  for (int off = 32; off; off >>= 1) s += __shfl_xor(s, off, 64);
  if ((threadIdx.x & 63) == 0) part[blockIdx.x * 4 + (threadIdx.x >> 6)] = s;
}

// ---------------- fused GEMM3 (N=10) + log-softmax + gather + sum ----------------
__global__ __launch_bounds__(256) void loss_kernel(const bf16* __restrict__ h2,
                                                   const bf16* __restrict__ W3b,
                                                   const float* __restrict__ b3,
                                                   const int* __restrict__ Y,
                                                   float* __restrict__ part) {
  __shared__ bf16 w3s[10 * HID];
  for (int i = threadIdx.x; i < 10 * HID / 8; i += 256)
    ((bf16x8*)w3s)[i] = ((const bf16x8*)W3b)[i];
  __syncthreads();

  const int lane = threadIdx.x & 63;
  const int w = threadIdx.x >> 6;
  const int nwave = gridDim.x * 4;
  float lsum = 0.f;

  for (int row = blockIdx.x * 4 + w; row < NROWS; row += nwave) {
    float p[10];
#pragma unroll
    for (int c = 0; c < 10; ++c) p[c] = 0.f;
    const bf16* hrow = h2 + (size_t)row * HID;
#pragma unroll
    for (int it = 0; it < 4; ++it) {
      const int k = it * 512 + lane * 8;
      bf16x8 hv = *(const bf16x8*)&hrow[k];
      float hf[8];
#pragma unroll
      for (int j = 0; j < 8; ++j) hf[j] = (float)hv[j];
#pragma unroll
      for (int c = 0; c < 10; ++c) {
        bf16x8 wv = *(const bf16x8*)&w3s[c * HID + k];
        float dp = 0.f;
#pragma unroll
        for (int j = 0; j < 8; ++j) dp += hf[j] * (float)wv[j];
        p[c] += dp;
      }
    }
#pragma unroll
    for (int off = 32; off; off >>= 1)
#pragma unroll
      for (int c = 0; c < 10; ++c) p[c] += __shfl_xor(p[c], off, 64);

    float lg[10], m = -1e30f;
#pragma unroll
    for (int c = 0; c < 10; ++c) { lg[c] = p[c] + b3[c]; m = fmaxf(m, lg[c]); }
    float s = 0.f;
#pragma unroll
    for (int c = 0; c < 10; ++c) s += expf(lg[c] - m);
    const float lse = m + logf(s);
    const int y = Y[row];
    float ly = 0.f;
#pragma unroll
    for (int c = 0; c < 10; ++c) ly += (c == y) ? lg[c] : 0.f;
    lsum += ly - lse;
  }
  if (lane == 0) part[blockIdx.x * 4 + w] = lsum;
}

// ---------------- finalize: reduce partials, compose output ----------------
// part layout: [0..8191] cvt sumsq partials, [8192..12287] loss partials
__global__ __launch_bounds__(256) void finalize_kernel(float* __restrict__ out,
                                                       const float* __restrict__ part,
                                                       const float* __restrict__ b3,
                                                       double dterm) {
  __shared__ float red[8];
  float sq = 0.f, ll = 0.f;
  for (int i = threadIdx.x; i < 8192; i += 256) sq += part[i];
  for (int i = threadIdx.x; i < 4096; i += 256) ll += part[8192 + i];
#pragma unroll
  for (int off = 32; off; off >>= 1) {
    sq += __shfl_xor(sq, off, 64);
    ll += __shfl_xor(ll, off, 64);
  }
  const int w = threadIdx.x >> 6;
  if ((threadIdx.x & 63) == 0) { red[w] = sq; red[4 + w] = ll; }
  __syncthreads();
  if (threadIdx.x == 0) {
    double sqd = (double)red[0] + red[1] + red[2] + red[3];
    double lld = (double)red[4] + red[5] + red[6] + red[7];
    for (int i = 0; i < 10; ++i) sqd += (double)b3[i] * (double)b3[i];
    out[0] = (float)(lld - 0.5 * (sqd / 100.0 + dterm));
  }
}

// ---------------- launch ----------------
extern "C" void kernel_launch(void* const* d_in, const int* in_sizes, int n_in,
                              void* d_out, int out_size, void* d_ws, size_t ws_size,
                              hipStream_t stream) {
  const float* X  = (const float*)d_in[0];
  const int*   Y  = (const int*)d_in[1];
  const float* W1 = (const float*)d_in[2];
  const float* b1 = (const float*)d_in[3];
  const float* W2 = (const float*)d_in[4];
  const float* b2 = (const float*)d_in[5];
  const float* W3 = (const float*)d_in[6];
  const float* b3 = (const float*)d_in[7];
  float* out = (float*)d_out;

  char* ws = (char*)d_ws;
  size_t off = 0;
  auto alloc = [&](size_t bytes) -> void* {
    void* p = ws + off;
    off += (bytes + 255) & ~(size_t)255;
    return p;
  };
  bf16* Xb  = (bf16*)alloc((size_t)NROWS * 1024 * 2);
  bf16* W1b = (bf16*)alloc((size_t)HID * 1024 * 2);
  bf16* W2b = (bf16*)alloc((size_t)HID * HID * 2);
  bf16* W3b = (bf16*)alloc((size_t)10 * HID * 2);
  bf16* h1  = (bf16*)alloc((size_t)NROWS * HID * 2);
  bf16* h2  = (bf16*)alloc((size_t)NROWS * HID * 2);
  float* part = (float*)alloc(12288 * 4);   // 8192 cvt + 4096 loss partials

  // fused convert + sum-of-squares (b3 handled in finalize)
  CvtSqArgs ca;
  ca.src[0] = X;  ca.dst[0] = Xb;  ca.n4[0] = NROWS * 1024 / 4; ca.dosq[0] = 0;
  ca.src[1] = W1; ca.dst[1] = W1b; ca.n4[1] = HID * 1024 / 4;   ca.dosq[1] = 1;
  ca.src[2] = W2; ca.dst[2] = W2b; ca.n4[2] = HID * HID / 4;    ca.dosq[2] = 1;
  ca.src[3] = W3; ca.dst[3] = W3b; ca.n4[3] = 10 * HID / 4;     ca.dosq[3] = 1;
  ca.src[4] = b1; ca.dst[4] = nullptr; ca.n4[4] = HID / 4;      ca.dosq[4] = 1;
  ca.src[5] = b2; ca.dst[5] = nullptr; ca.n4[5] = HID / 4;      ca.dosq[5] = 1;
  cvtsq_kernel<<<2048, 256, 0, stream>>>(ca, part);

  hipFuncSetAttribute((const void*)gemm_r6<1024, true>,
                      hipFuncAttributeMaxDynamicSharedMemorySize, 131072);
  hipFuncSetAttribute((const void*)gemm_p4<2048, true>,
                      hipFuncAttributeMaxDynamicSharedMemorySize, 131072);

  // GEMM1: h1 = relu(X[16384,1024] * W1[2048,1024]^T + b1)  (round-6 kernel)
  gemm_r6<1024, true><<<512, 512, 131072, stream>>>(Xb, W1b, b1, h1, HID);
  // GEMM2: h2 = relu(h1 * W2[2048,2048]^T + b2)  (m201 4-phase port)
  gemm_p4<2048, true><<<512, 512, 131072, stream>>>(h1, W2b, b2, h2, HID);

  loss_kernel<<<1024, 256, 0, stream>>>(h2, W3b, b3, Y, part + 8192);

  long long d = 0;
  for (int i = 2; i < 8; ++i) d += in_sizes[i];
  double dterm = (double)d * log(2.0 * M_PI * 100.0);
  finalize_kernel<<<1, 256, 0, stream>>>(out, part, b3, dterm);
}